// Round 8
// baseline (218.099 us; speedup 1.0000x reference)
//
#include <hip/hip_runtime.h>

// MultiScaleTrendLoss, exact chunked-scan, float4 lanes + high TLP.
//
// loss = mean_{b,f} sum_a w_a * mean_t EMA_a(pred-target)[b,t,f]^2
// EMA linearity: EMA(pred)-EMA(target) == EMA(d), d = pred-target.
//
// Chunk algebra (exact, absmax=0 proven): z = zero-init EMA within chunk;
// with carry-in e, y_k = z_k + r^{k+1} e, so
//   sum y^2 = A + 2eB + e^2 C,  A=sum z^2, B=sum z_k r^{k+1},
//   C=r^2(1-r^{2L})/(1-r^2),  carry-out e' = z_{L-1} + r^L e.
// Chunk 0 (y_0 = d_0) == uniform recurrence with carry-in e = d_0.
//
// Round-6 lesson: per-wave ILP (float4 x 16-deep pipeline) does NOT raise
// BW past ~2.9 TB/s at 1 wave/SIMD -- effective in-flight bytes per CU was
// ~4 KB across three different ILP structures.  In-flight capacity scales
// with WAVES (m13's 6.29 TB/s copy runs at full occupancy).  So: NCHUNK=256
// (CHUNK=16) -> 4096 waves = 16/CU = 4/SIMD (VGPR 124 allows exactly 4).

#define T_LEN 4096
#define F_LEN 64
#define NB    64
#define NPAIR 4096

constexpr double powd(double r, int n) {
    double v = 1.0, b = r;
    while (n > 0) { if (n & 1) v *= b; b *= b; n >>= 1; }
    return v;
}

// ---------------------------------------------------------------- pass 1
template<int NCHUNK>
__global__ __launch_bounds__(64)
void mstl_pass1(const float4* __restrict__ pred,
                const float4* __restrict__ targ,
                float* __restrict__ ws)
{
    constexpr int CHUNK = T_LEN / NCHUNK;
    constexpr int NSTG  = CHUNK / 4;          // 4 timesteps per stage
    constexpr float R0 = 0.9f, R1 = 0.7f, R2 = 0.5f;
    constexpr float A0 = 0.1f, A1 = 0.3f, A2 = 0.5f;

    const int lane = threadIdx.x;
    const int g    = lane >> 4;               // task slot 0..3
    const int fl   = lane & 15;               // feature quad (4*fl..4*fl+3)
    const int task = blockIdx.x * 4 + g;
    const int b    = task / NCHUNK;
    const int c    = task % NCHUNK;

    // row of 64 floats = 16 float4; lane fl covers its quad
    const float4* __restrict__ p = pred + (size_t)(b * T_LEN + c * CHUNK) * 16 + fl;
    const float4* __restrict__ q = targ + (size_t)(b * T_LEN + c * CHUNK) * 16 + fl;

    float4 z0{0,0,0,0}, z1{0,0,0,0}, z2{0,0,0,0};
    float4 a0{0,0,0,0}, a1{0,0,0,0}, a2{0,0,0,0};
    float4 b0{0,0,0,0}, b1{0,0,0,0}, b2{0,0,0,0};
    float  w0 = R0, w1 = R1, w2 = R2;         // r^{k+1}

    float4 pA0,pA1,pA2,pA3, qA0,qA1,qA2,qA3;  // named stages, static idx only
    float4 pB0,pB1,pB2,pB3, qB0,qB1,qB2,qB3;

#define LOADA(t0) { pA0=p[(size_t)(t0)*16];     pA1=p[(size_t)((t0)+1)*16]; \
                    pA2=p[(size_t)((t0)+2)*16]; pA3=p[(size_t)((t0)+3)*16]; \
                    qA0=q[(size_t)(t0)*16];     qA1=q[(size_t)((t0)+1)*16]; \
                    qA2=q[(size_t)((t0)+2)*16]; qA3=q[(size_t)((t0)+3)*16]; }
#define LOADB(t0) { pB0=p[(size_t)(t0)*16];     pB1=p[(size_t)((t0)+1)*16]; \
                    pB2=p[(size_t)((t0)+2)*16]; pB3=p[(size_t)((t0)+3)*16]; \
                    qB0=q[(size_t)(t0)*16];     qB1=q[(size_t)((t0)+1)*16]; \
                    qB2=q[(size_t)((t0)+2)*16]; qB3=q[(size_t)((t0)+3)*16]; }
#define STEP(P,Q) { \
    const float dx=(P).x-(Q).x, dy=(P).y-(Q).y, dz=(P).z-(Q).z, dw=(P).w-(Q).w; \
    z0.x=fmaf(R0,z0.x,A0*dx); a0.x=fmaf(z0.x,z0.x,a0.x); b0.x=fmaf(z0.x,w0,b0.x); \
    z0.y=fmaf(R0,z0.y,A0*dy); a0.y=fmaf(z0.y,z0.y,a0.y); b0.y=fmaf(z0.y,w0,b0.y); \
    z0.z=fmaf(R0,z0.z,A0*dz); a0.z=fmaf(z0.z,z0.z,a0.z); b0.z=fmaf(z0.z,w0,b0.z); \
    z0.w=fmaf(R0,z0.w,A0*dw); a0.w=fmaf(z0.w,z0.w,a0.w); b0.w=fmaf(z0.w,w0,b0.w); \
    w0 *= R0; \
    z1.x=fmaf(R1,z1.x,A1*dx); a1.x=fmaf(z1.x,z1.x,a1.x); b1.x=fmaf(z1.x,w1,b1.x); \
    z1.y=fmaf(R1,z1.y,A1*dy); a1.y=fmaf(z1.y,z1.y,a1.y); b1.y=fmaf(z1.y,w1,b1.y); \
    z1.z=fmaf(R1,z1.z,A1*dz); a1.z=fmaf(z1.z,z1.z,a1.z); b1.z=fmaf(z1.z,w1,b1.z); \
    z1.w=fmaf(R1,z1.w,A1*dw); a1.w=fmaf(z1.w,z1.w,a1.w); b1.w=fmaf(z1.w,w1,b1.w); \
    w1 *= R1; \
    z2.x=fmaf(R2,z2.x,A2*dx); a2.x=fmaf(z2.x,z2.x,a2.x); b2.x=fmaf(z2.x,w2,b2.x); \
    z2.y=fmaf(R2,z2.y,A2*dy); a2.y=fmaf(z2.y,z2.y,a2.y); b2.y=fmaf(z2.y,w2,b2.y); \
    z2.z=fmaf(R2,z2.z,A2*dz); a2.z=fmaf(z2.z,z2.z,a2.z); b2.z=fmaf(z2.z,w2,b2.z); \
    z2.w=fmaf(R2,z2.w,A2*dw); a2.w=fmaf(z2.w,z2.w,a2.w); b2.w=fmaf(z2.w,w2,b2.w); \
    w2 *= R2; }
#define COMPA() { STEP(pA0,qA0) STEP(pA1,qA1) STEP(pA2,qA2) STEP(pA3,qA3) }
#define COMPB() { STEP(pB0,qB0) STEP(pB1,qB1) STEP(pB2,qB2) STEP(pB3,qB3) }

    LOADA(0);
    #pragma unroll
    for (int s = 0; s < NSTG; s += 2) {
        LOADB((s + 1) * 4);
        COMPA();
        if (s + 2 < NSTG) LOADA((s + 2) * 4);
        COMPB();
    }
#undef LOADA
#undef LOADB
#undef STEP
#undef COMPA
#undef COMPB

    // stats: slot s in 0..8, layout ws[(s*NCHUNK + c)*NPAIR + b*64 + 4*fl]
    const int pf = b * F_LEN + fl * 4;        // 16 B aligned
#define ST(slot, val) *(float4*)(ws + ((size_t)(slot) * NCHUNK + c) * NPAIR + pf) = (val);
    ST(0, a0) ST(1, b0) ST(2, z0)
    ST(3, a1) ST(4, b1) ST(5, z1)
    ST(6, a2) ST(7, b2) ST(8, z2)
#undef ST
}

// ---------------------------------------------------------------- pass 2
template<int NCHUNK>
__global__ __launch_bounds__(64)
void mstl_pass2(const float* __restrict__ ws,
                const float* __restrict__ pred,
                const float* __restrict__ targ,
                float* __restrict__ out)
{
    constexpr int CHUNK = T_LEN / NCHUNK;
    constexpr float RL[3] = { (float)powd(0.9, CHUNK), (float)powd(0.7, CHUNK),
                              (float)powd(0.5, CHUNK) };
    constexpr float CC[3] = {
        (float)(0.81 * (1.0 - powd(0.9, 2*CHUNK)) / (1.0 - 0.81)),
        (float)(0.49 * (1.0 - powd(0.7, 2*CHUNK)) / (1.0 - 0.49)),
        (float)(0.25 * (1.0 - powd(0.5, 2*CHUNK)) / (1.0 - 0.25)) };
    constexpr float WGT[3] = { 0.5f, 0.3f, 0.2f };

    const int a   = blockIdx.x >> 6;          // alpha index (block-uniform)
    const int pfb = blockIdx.x & 63;
    const int pf  = pfb * 64 + threadIdx.x;   // (b,f) pair
    const int b   = pf >> 6, f = pf & 63;

    const float rl = (a == 0) ? RL[0] : (a == 1) ? RL[1] : RL[2];
    const float cc = (a == 0) ? CC[0] : (a == 1) ? CC[1] : CC[2];
    const float wg = (a == 0) ? WGT[0] : (a == 1) ? WGT[1] : WGT[2];

    // carry-in for chunk 0 is d_0
    const size_t row0 = (size_t)b * T_LEN * F_LEN + f;
    float e = pred[row0] - targ[row0];

    const float* __restrict__ base = ws + (size_t)(a * 3) * NCHUNK * NPAIR + pf;

    float s = 0.f;
    #pragma unroll 16
    for (int c = 0; c < NCHUNK; ++c) {
        float A = base[((size_t)0 * NCHUNK + c) * NPAIR];
        float B = base[((size_t)1 * NCHUNK + c) * NPAIR];
        float Z = base[((size_t)2 * NCHUNK + c) * NPAIR];
        s += A + e * (2.f * B + e * cc);
        e = fmaf(rl, e, Z);
    }

    float total = s * wg;
    #pragma unroll
    for (int off = 32; off > 0; off >>= 1)
        total += __shfl_down(total, off, 64);

    if (threadIdx.x == 0)
        atomicAdd(out, total * (1.0f / 16777216.0f));   // / (T * B * F)
}

// ---------------------------------------------------------------- launch
extern "C" void kernel_launch(void* const* d_in, const int* in_sizes, int n_in,
                              void* d_out, int out_size, void* d_ws, size_t ws_size,
                              hipStream_t stream) {
    const float* pred = (const float*)d_in[0];
    const float* targ = (const float*)d_in[1];
    float* out = (float*)d_out;
    float* ws  = (float*)d_ws;

    hipMemsetAsync(out, 0, sizeof(float) * out_size, stream);

    const size_t need256 = (size_t)9 * 256 * NPAIR * sizeof(float);  // 37.7 MB
    const size_t need128 = (size_t)9 * 128 * NPAIR * sizeof(float);  // 18.9 MB
    if (ws_size >= need256) {
        mstl_pass1<256><<<dim3(NB * 256 / 4), dim3(64), 0, stream>>>(
            (const float4*)pred, (const float4*)targ, ws);
        mstl_pass2<256><<<dim3(192), dim3(64), 0, stream>>>(ws, pred, targ, out);
    } else if (ws_size >= need128) {
        mstl_pass1<128><<<dim3(NB * 128 / 4), dim3(64), 0, stream>>>(
            (const float4*)pred, (const float4*)targ, ws);
        mstl_pass2<128><<<dim3(192), dim3(64), 0, stream>>>(ws, pred, targ, out);
    } else {  // 9.44 MB footprint (proven available in rounds 5/6)
        mstl_pass1<64><<<dim3(NB * 64 / 4), dim3(64), 0, stream>>>(
            (const float4*)pred, (const float4*)targ, ws);
        mstl_pass2<64><<<dim3(192), dim3(64), 0, stream>>>(ws, pred, targ, out);
    }
}

// Round 9
// 167.380 us; speedup vs baseline: 1.3030x; 1.3030x over previous
//
#include <hip/hip_runtime.h>

// MultiScaleTrendLoss, exact chunked-scan, hierarchical splice.
//
// loss = mean_{b,f} sum_a w_a * mean_t EMA_a(pred-target)[b,t,f]^2
// EMA linearity: EMA(pred)-EMA(target) == EMA(d), d = pred-target.
//
// Chunk algebra (exact, absmax=0 proven): z = zero-init EMA within chunk;
// with carry-in e, y_k = z_k + r^{k+1} e, so
//   sum y^2 = A + 2eB + e^2 cA,  A=sum z^2, B=sum z_k r^{k+1},
//   cA=r^2(1-r^{2L})/(1-r^2),  carry-out e' = z_{L-1} + r^L e.
// Chunk 0 (y_0 = d_0) == uniform recurrence with carry-in e = d_0.
//
// Round-8 lesson: pass2 with 192 waves x 256 serial chunks = 63 us
// (1.9% occupancy, latency-bound).  The splice recurrence is linear in the
// carry with constant factor rl = r^CHUNK, so it composes hierarchically:
// segment of CPS chunks with carry-in E has e_c = u_c + rl^c E, giving
//   A' = sum A_c + 2 sum u_c B_c + cA sum u_c^2
//   B' = sum rl^c (B_c + cA u_c)
//   C' = cA * sum_{c<CPS} rl^{2c}          (compile-time)
//   Z' = u_CPS,  carry factor rl^CPS.
// pass2a: 3072 waves splice 16-chunk segments; pass2b: 192 waves splice
// the 16 segments.  Both exact.

#define T_LEN 4096
#define F_LEN 64
#define NB    64
#define NPAIR 4096
#define SEGS  16

constexpr double powd(double r, int n) {
    double v = 1.0, b = r;
    while (n > 0) { if (n & 1) v *= b; b *= b; n >>= 1; }
    return v;
}
constexpr double RAD[3] = {0.9, 0.7, 0.5};            // r per alpha
constexpr float  WGT[3] = {0.5f, 0.3f, 0.2f};

// ---------------------------------------------------------------- pass 1
template<int NCHUNK>
__global__ __launch_bounds__(64)
void mstl_pass1(const float4* __restrict__ pred,
                const float4* __restrict__ targ,
                float* __restrict__ ws)
{
    constexpr int CHUNK = T_LEN / NCHUNK;
    constexpr int NSTG  = CHUNK / 4;          // 4 timesteps per stage
    constexpr float R0 = 0.9f, R1 = 0.7f, R2 = 0.5f;
    constexpr float A0 = 0.1f, A1 = 0.3f, A2 = 0.5f;

    const int lane = threadIdx.x;
    const int g    = lane >> 4;               // task slot 0..3
    const int fl   = lane & 15;               // feature quad (4*fl..4*fl+3)
    const int task = blockIdx.x * 4 + g;
    const int b    = task / NCHUNK;
    const int c    = task % NCHUNK;

    const float4* __restrict__ p = pred + (size_t)(b * T_LEN + c * CHUNK) * 16 + fl;
    const float4* __restrict__ q = targ + (size_t)(b * T_LEN + c * CHUNK) * 16 + fl;

    float4 z0{0,0,0,0}, z1{0,0,0,0}, z2{0,0,0,0};
    float4 a0{0,0,0,0}, a1{0,0,0,0}, a2{0,0,0,0};
    float4 b0{0,0,0,0}, b1{0,0,0,0}, b2{0,0,0,0};
    float  w0 = R0, w1 = R1, w2 = R2;         // r^{k+1}

    float4 pA0,pA1,pA2,pA3, qA0,qA1,qA2,qA3;  // named stages, static idx only
    float4 pB0,pB1,pB2,pB3, qB0,qB1,qB2,qB3;

#define LOADA(t0) { pA0=p[(size_t)(t0)*16];     pA1=p[(size_t)((t0)+1)*16]; \
                    pA2=p[(size_t)((t0)+2)*16]; pA3=p[(size_t)((t0)+3)*16]; \
                    qA0=q[(size_t)(t0)*16];     qA1=q[(size_t)((t0)+1)*16]; \
                    qA2=q[(size_t)((t0)+2)*16]; qA3=q[(size_t)((t0)+3)*16]; }
#define LOADB(t0) { pB0=p[(size_t)(t0)*16];     pB1=p[(size_t)((t0)+1)*16]; \
                    pB2=p[(size_t)((t0)+2)*16]; pB3=p[(size_t)((t0)+3)*16]; \
                    qB0=q[(size_t)(t0)*16];     qB1=q[(size_t)((t0)+1)*16]; \
                    qB2=q[(size_t)((t0)+2)*16]; qB3=q[(size_t)((t0)+3)*16]; }
#define STEP(P,Q) { \
    const float dx=(P).x-(Q).x, dy=(P).y-(Q).y, dz=(P).z-(Q).z, dw=(P).w-(Q).w; \
    z0.x=fmaf(R0,z0.x,A0*dx); a0.x=fmaf(z0.x,z0.x,a0.x); b0.x=fmaf(z0.x,w0,b0.x); \
    z0.y=fmaf(R0,z0.y,A0*dy); a0.y=fmaf(z0.y,z0.y,a0.y); b0.y=fmaf(z0.y,w0,b0.y); \
    z0.z=fmaf(R0,z0.z,A0*dz); a0.z=fmaf(z0.z,z0.z,a0.z); b0.z=fmaf(z0.z,w0,b0.z); \
    z0.w=fmaf(R0,z0.w,A0*dw); a0.w=fmaf(z0.w,z0.w,a0.w); b0.w=fmaf(z0.w,w0,b0.w); \
    w0 *= R0; \
    z1.x=fmaf(R1,z1.x,A1*dx); a1.x=fmaf(z1.x,z1.x,a1.x); b1.x=fmaf(z1.x,w1,b1.x); \
    z1.y=fmaf(R1,z1.y,A1*dy); a1.y=fmaf(z1.y,z1.y,a1.y); b1.y=fmaf(z1.y,w1,b1.y); \
    z1.z=fmaf(R1,z1.z,A1*dz); a1.z=fmaf(z1.z,z1.z,a1.z); b1.z=fmaf(z1.z,w1,b1.z); \
    z1.w=fmaf(R1,z1.w,A1*dw); a1.w=fmaf(z1.w,z1.w,a1.w); b1.w=fmaf(z1.w,w1,b1.w); \
    w1 *= R1; \
    z2.x=fmaf(R2,z2.x,A2*dx); a2.x=fmaf(z2.x,z2.x,a2.x); b2.x=fmaf(z2.x,w2,b2.x); \
    z2.y=fmaf(R2,z2.y,A2*dy); a2.y=fmaf(z2.y,z2.y,a2.y); b2.y=fmaf(z2.y,w2,b2.y); \
    z2.z=fmaf(R2,z2.z,A2*dz); a2.z=fmaf(z2.z,z2.z,a2.z); b2.z=fmaf(z2.z,w2,b2.z); \
    z2.w=fmaf(R2,z2.w,A2*dw); a2.w=fmaf(z2.w,z2.w,a2.w); b2.w=fmaf(z2.w,w2,b2.w); \
    w2 *= R2; }
#define COMPA() { STEP(pA0,qA0) STEP(pA1,qA1) STEP(pA2,qA2) STEP(pA3,qA3) }
#define COMPB() { STEP(pB0,qB0) STEP(pB1,qB1) STEP(pB2,qB2) STEP(pB3,qB3) }

    LOADA(0);
    #pragma unroll
    for (int s = 0; s < NSTG; s += 2) {
        LOADB((s + 1) * 4);
        COMPA();
        if (s + 2 < NSTG) LOADA((s + 2) * 4);
        COMPB();
    }
#undef LOADA
#undef LOADB
#undef STEP
#undef COMPA
#undef COMPB

    // stats: slot = alpha*3 + {A=0,B=1,Z=2}; ws[(slot*NCHUNK + c)*NPAIR + pf]
    const int pf = b * F_LEN + fl * 4;        // 16 B aligned
#define ST(slot, val) *(float4*)(ws + ((size_t)(slot) * NCHUNK + c) * NPAIR + pf) = (val);
    ST(0, a0) ST(1, b0) ST(2, z0)
    ST(3, a1) ST(4, b1) ST(5, z1)
    ST(6, a2) ST(7, b2) ST(8, z2)
#undef ST
}

// ------------------------------------------------------- pass 2a (segments)
// ws2 layout: ws2[((a*SEGS + s)*3 + stat)*NPAIR + pf], stat {A'=0,B'=1,Z'=2}
template<int NCHUNK>
__global__ __launch_bounds__(64)
void mstl_pass2a(const float* __restrict__ ws, float* __restrict__ ws2)
{
    constexpr int CPS   = NCHUNK / SEGS;      // chunks per segment
    constexpr int CHUNK = T_LEN / NCHUNK;
    constexpr float RLv[3] = { (float)powd(RAD[0], CHUNK), (float)powd(RAD[1], CHUNK),
                               (float)powd(RAD[2], CHUNK) };
    constexpr float CAv[3] = {
        (float)(RAD[0]*RAD[0] * (1.0 - powd(RAD[0], 2*CHUNK)) / (1.0 - RAD[0]*RAD[0])),
        (float)(RAD[1]*RAD[1] * (1.0 - powd(RAD[1], 2*CHUNK)) / (1.0 - RAD[1]*RAD[1])),
        (float)(RAD[2]*RAD[2] * (1.0 - powd(RAD[2], 2*CHUNK)) / (1.0 - RAD[2]*RAD[2])) };

    const int bid = blockIdx.x;
    const int a   = bid >> 10;                // / (SEGS*64)
    const int rem = bid & 1023;
    const int s   = rem >> 6;                 // segment
    const int pfb = rem & 63;
    const int pf  = pfb * 64 + threadIdx.x;

    const float rl = (a == 0) ? RLv[0] : (a == 1) ? RLv[1] : RLv[2];
    const float cA = (a == 0) ? CAv[0] : (a == 1) ? CAv[1] : CAv[2];

    const float* __restrict__ base = ws + (size_t)(a * 3) * NCHUNK * NPAIR + pf;

    float u = 0.f, Ap = 0.f, Bp = 0.f, w = 1.f;   // w = rl^c
    #pragma unroll
    for (int c = 0; c < CPS; ++c) {
        const int gc = s * CPS + c;
        float A = base[((size_t)0 * NCHUNK + gc) * NPAIR];
        float B = base[((size_t)1 * NCHUNK + gc) * NPAIR];
        float Z = base[((size_t)2 * NCHUNK + gc) * NPAIR];
        Ap += A + u * (2.f * B + cA * u);
        Bp += w * (B + cA * u);
        u   = fmaf(rl, u, Z);
        w  *= rl;
    }

    float* o = ws2 + ((size_t)(a * SEGS + s) * 3) * NPAIR + pf;
    o[(size_t)0 * NPAIR] = Ap;
    o[(size_t)1 * NPAIR] = Bp;
    o[(size_t)2 * NPAIR] = u;                 // Z' = u_CPS
}

// ------------------------------------------------------- pass 2b (splice)
template<int NCHUNK>
__global__ __launch_bounds__(64)
void mstl_pass2b(const float* __restrict__ ws2,
                 const float* __restrict__ pred,
                 const float* __restrict__ targ,
                 float* __restrict__ out)
{
    constexpr int CPS   = NCHUNK / SEGS;
    constexpr int CHUNK = T_LEN / NCHUNK;
    // per-alpha: rls = rl^CPS = r^(T_LEN/SEGS); CP = cA * sum_{c<CPS} rl^{2c}
    constexpr float RLS[3] = { (float)powd(RAD[0], CHUNK*CPS), (float)powd(RAD[1], CHUNK*CPS),
                               (float)powd(RAD[2], CHUNK*CPS) };
    constexpr double rl2_0 = powd(RAD[0], 2*CHUNK), rl2_1 = powd(RAD[1], 2*CHUNK),
                     rl2_2 = powd(RAD[2], 2*CHUNK);
    constexpr float CP[3] = {
        (float)((RAD[0]*RAD[0] * (1.0 - powd(RAD[0], 2*CHUNK)) / (1.0 - RAD[0]*RAD[0]))
                * (1.0 - powd(rl2_0, CPS)) / (1.0 - rl2_0)),
        (float)((RAD[1]*RAD[1] * (1.0 - powd(RAD[1], 2*CHUNK)) / (1.0 - RAD[1]*RAD[1]))
                * (1.0 - powd(rl2_1, CPS)) / (1.0 - rl2_1)),
        (float)((RAD[2]*RAD[2] * (1.0 - powd(RAD[2], 2*CHUNK)) / (1.0 - RAD[2]*RAD[2]))
                * (1.0 - powd(rl2_2, CPS)) / (1.0 - rl2_2)) };

    const int a   = blockIdx.x >> 6;
    const int pfb = blockIdx.x & 63;
    const int pf  = pfb * 64 + threadIdx.x;
    const int b   = pf >> 6, f = pf & 63;

    const float rls = (a == 0) ? RLS[0] : (a == 1) ? RLS[1] : RLS[2];
    const float cp  = (a == 0) ? CP[0]  : (a == 1) ? CP[1]  : CP[2];
    const float wg  = (a == 0) ? WGT[0] : (a == 1) ? WGT[1] : WGT[2];

    // carry-in for the whole sequence is d_0
    const size_t row0 = (size_t)b * T_LEN * F_LEN + f;
    float e = pred[row0] - targ[row0];

    float S = 0.f;
    #pragma unroll
    for (int s = 0; s < SEGS; ++s) {
        const float* o = ws2 + ((size_t)(a * SEGS + s) * 3) * NPAIR + pf;
        float Ap = o[(size_t)0 * NPAIR];
        float Bp = o[(size_t)1 * NPAIR];
        float Zp = o[(size_t)2 * NPAIR];
        S += Ap + e * (2.f * Bp + cp * e);
        e  = fmaf(rls, e, Zp);
    }

    float total = S * wg;
    #pragma unroll
    for (int off = 32; off > 0; off >>= 1)
        total += __shfl_down(total, off, 64);

    if (threadIdx.x == 0)
        atomicAdd(out, total * (1.0f / 16777216.0f));   // / (T * B * F)
}

// ---------------------------------------------------------------- launch
template<int NCHUNK>
static void launch_all(const float* pred, const float* targ,
                       float* out, float* ws, hipStream_t stream) {
    float* ws2 = ws + (size_t)9 * NCHUNK * NPAIR;     // segment stats (2.36 MB)
    mstl_pass1<NCHUNK><<<dim3(NB * NCHUNK / 4), dim3(64), 0, stream>>>(
        (const float4*)pred, (const float4*)targ, ws);
    mstl_pass2a<NCHUNK><<<dim3(3 * SEGS * 64), dim3(64), 0, stream>>>(ws, ws2);
    mstl_pass2b<NCHUNK><<<dim3(192), dim3(64), 0, stream>>>(ws2, pred, targ, out);
}

extern "C" void kernel_launch(void* const* d_in, const int* in_sizes, int n_in,
                              void* d_out, int out_size, void* d_ws, size_t ws_size,
                              hipStream_t stream) {
    const float* pred = (const float*)d_in[0];
    const float* targ = (const float*)d_in[1];
    float* out = (float*)d_out;
    float* ws  = (float*)d_ws;

    hipMemsetAsync(out, 0, sizeof(float) * out_size, stream);

    auto need = [](int nchunk) {
        return (size_t)(9 * nchunk + 3 * SEGS * 3) * NPAIR * sizeof(float);
    };
    if      (ws_size >= need(256)) launch_all<256>(pred, targ, out, ws, stream);
    else if (ws_size >= need(128)) launch_all<128>(pred, targ, out, ws, stream);
    else if (ws_size >= need(64))  launch_all<64>(pred, targ, out, ws, stream);
    else                           launch_all<32>(pred, targ, out, ws, stream);
}